// Round 15
// baseline (308.553 us; speedup 1.0000x reference)
//
#include <hip/hip_runtime.h>
#include <math.h>

#define GXD 128
#define GYD 128
#define GZD 32
#define DD  64
#define GCELLS (GXD * GYD * GZD)   // 524288

#define MINX (-20.0f)
#define MINY (-20.0f)
#define MINZ (-2.0f)
#define VOXX (0.3125f)
#define VOXY (0.3125f)
#define VOXZ (0.25f)
#define ELL  (0.5f)
#define EPSV (1e-6f)
#define PIF  (3.14159265358979323846f)

typedef float v2f __attribute__((ext_vector_type(2)));
typedef float v4f __attribute__((ext_vector_type(4)));

// Column weights: for the 9 (ox,oy) columns, w0 = kval at oz=0, w1 = kval at
// |oz|=1. Corners (|ox|=|oy|=1) have w1 == 0 (d >= ELL). c = (ox+1)*3+(oy+1).
struct KvCols { float w0[9]; float w1[9]; };
#define IS_PLUS(c) ((c) == 1 || (c) == 3 || (c) == 4 || (c) == 5 || (c) == 7)

// ---------------------------------------------------------------------------
__device__ __forceinline__ float kval_of(int o) {   // fallback path only
    int ox = o / 9 - 1;
    int oy = (o / 3) % 3 - 1;
    int oz = o % 3 - 1;
    float dx = ox * VOXX, dy = oy * VOXY, dz = oz * VOXZ;
    float d = sqrtf(dx * dx + dy * dy + dz * dz);
    float ang = 2.0f * PIF * d / ELL;
    float v = (1.0f / 3.0f) * (2.0f + cosf(ang)) * (1.0f - d / ELL)
            + (1.0f / (2.0f * PIF)) * sinf(ang);
    v = (d >= ELL) ? 0.0f : v;
    return fminf(fmaxf(v, 0.0f), 1.0f);
}

__device__ __forceinline__ int base_cell(const float* __restrict__ row,
                                         int* cx, int* cy, int* cz) {
    float x = row[0], y = row[1], z = row[2];
    int gx = (int)floorf((x - MINX) / VOXX);
    int gy = (int)floorf((y - MINY) / VOXY);
    int gz = (int)floorf((z - MINZ) / VOXZ);
    gx = min(max(gx, 0), GXD - 1);
    gy = min(max(gy, 0), GYD - 1);
    gz = min(max(gz, 0), GZD - 1);
    *cx = gx; *cy = gy; *cz = gz;
    return (gx * GYD + gy) * GZD + gz;
}

// ===========================================================================
// FAST PATH — workspace (floats), FLAT layout (compact atomics):
//   M0 : [0, GCELLS)            cell counts (memset)
//   MM : [cell][feature][m1,m2] = 512B/cell; + 8192-float zero sentinel pad
//        (stencil reads dwordx4 at pairBase + lane*16: lanes 0-31 = even
//         cell's features 2l,2l+1; lanes 32-63 = odd cell's)
// ===========================================================================

// Pass 1: zero own row AND partner row of the z-pair (a pair is gathered if
// EITHER cell is occupied; races benign: everyone writes zeros, before build)
__global__ void lbki_zero_rows(const float* __restrict__ pc,
                               float2* __restrict__ MM2,
                               int npts) {
    int lane = threadIdx.x & 63;
    int wave = threadIdx.x >> 6;
    int p = blockIdx.x * (blockDim.x >> 6) + wave;
    if (p >= npts) return;
    int cx, cy, cz;
    int g = base_cell(pc + (size_t)p * 67, &cx, &cy, &cz);
    MM2[(size_t)g * DD + lane]       = make_float2(0.0f, 0.0f);
    MM2[(size_t)(g ^ 1) * DD + lane] = make_float2(0.0f, 0.0f);
}

// Pass 2: compact scatter (8B stride per lane)
__global__ void lbki_build(const float* __restrict__ pc,
                           float* __restrict__ M0,
                           float* __restrict__ MM,
                           int npts) {
    int lane = threadIdx.x & 63;
    int wave = threadIdx.x >> 6;
    int p = blockIdx.x * (blockDim.x >> 6) + wave;
    if (p >= npts) return;
    const float* row = pc + (size_t)p * 67;
    int cx, cy, cz;
    int g = base_cell(row, &cx, &cy, &cz);
    float f = row[3 + lane];
    size_t e = ((size_t)g * DD + lane) * 2;
    atomicAdd(&MM[e],     f);
    atomicAdd(&MM[e + 1], f * f);
    if (lane == 0) atomicAdd(&M0[g], 1.0f);
}

// z-column stencil fused with finalize. Block = 8 adjacent y-columns, one
// wave each. LANE-SPLIT: lanes 0-31 own even-z cells (features 2l,2l+1 each),
// lanes 32-63 own odd-z. One z-pair per step; w1 cross-parity terms exchanged
// with one shfl_xor(32) of the 4-dword partial. MAPS RING-OF-4: mean/var/conf
// prefetched 4 pair-steps (~1800 cy) ahead to cover HBM stream latency.
__global__ __launch_bounds__(512)
void lbki_stencil_colB(const float* __restrict__ M0,
                       const float* __restrict__ MM,
                       const float* __restrict__ mean_map,
                       const float* __restrict__ var_map,
                       const float* __restrict__ conf_map,
                       float* __restrict__ out_mean,
                       float* __restrict__ out_var,
                       float* __restrict__ out_conf,
                       KvCols ka) {
    __shared__ float    sm0[3 * 10 * 35];  // [xo][yo][zp], zp = z+1, pads zero
    __shared__ float    kb_lds[256];       // [col 0..7][z] precomputed k_bar
    __shared__ unsigned smask[30];         // per halo column: bit z = nonempty
    const int tid  = threadIdx.x;
    const int lane = tid & 63;
    const int wave = __builtin_amdgcn_readfirstlane(tid >> 6);
    const int half = lane >> 5;            // 0: even-z cells, 1: odd-z cells
    const int l5   = lane & 31;

    // bijective XCD swizzle (2048 blocks, % 8 == 0)
    unsigned bid = blockIdx.x;
    unsigned chunk = gridDim.x >> 3;
    unsigned swz = (bid & 7u) * chunk + (bid >> 3);
    const int col0 = (int)(swz * 8u);
    const int cx  = col0 >> 7;
    const int cy0 = col0 & 127;

    // ---- stage M0 halo into LDS: sm0[xo][yo][z+1], zeros outside ----
    for (int e = tid; e < 3 * 10 * 35; e += 512) {
        int xo = e / 350;
        int r  = e - xo * 350;
        int yo = r / 35;
        int zp = r - yo * 35;
        int z  = zp - 1;
        int gx_ = cx - 1 + xo;
        int gy_ = cy0 - 1 + yo;
        bool v = ((unsigned)gx_ < (unsigned)GXD) &&
                 ((unsigned)gy_ < (unsigned)GYD) && ((unsigned)z < (unsigned)GZD);
        float val = 0.0f;
        if (v) val = M0[((gx_ << 7) + gy_) * 32 + z];
        sm0[e] = val;
    }
    __syncthreads();

    // ---- once per block: k_bar + out_conf for 256 cells + 30 masks ----
    if (tid < 256) {
        int j = tid >> 5, z = tid & 31;
        float kb = 0.0f;
        #pragma unroll
        for (int c = 0; c < 9; ++c) {
            const float* sc = sm0 + ((c / 3) * 10 + j + c % 3) * 35 + z + 1;
            kb += ka.w0[c] * sc[0];
            if (IS_PLUS(c)) kb += ka.w1[c] * (sc[-1] + sc[1]);
        }
        kb_lds[(j << 5) + z] = kb;
        unsigned cell = (unsigned)((cx << 7) + cy0 + j) * 32u + (unsigned)z;
        out_conf[cell] = conf_map[cell] + kb;
    } else if (tid < 256 + 30) {
        int idx = tid - 256;
        const float* sc = sm0 + idx * 35 + 1;
        unsigned m = 0;
        for (int z = 0; z < 32; ++z)
            if (sc[z] != 0.0f) m |= (1u << z);
        smask[idx] = m;
    }
    __syncthreads();

    // ---- per-wave setup (wave-uniform -> SGPR) ----
    const int cy = cy0 + wave;
    const char* sentp = (const char*)MM + (size_t)GCELLS * 512u;  // 32KB pad

    unsigned long long mk[9];
    const char* tp[9];
    #pragma unroll
    for (int c = 0; c < 9; ++c) {
        unsigned mval = (unsigned)__builtin_amdgcn_readfirstlane(
                            (int)smask[(c / 3) * 10 + wave + c % 3]);
        mk[c] = (unsigned long long)mval;
        int nx = cx + c / 3 - 1;
        int ny = cy + c % 3 - 1;
        bool v = ((unsigned)nx < (unsigned)GXD) && ((unsigned)ny < (unsigned)GYD);
        tp[c] = v ? ((const char*)MM + (size_t)(((nx << 7) + ny) << 5) * 512u)
                  : sentp;
    }
    const int laneB = lane * 16;

    const unsigned gbase = (unsigned)((cx << 7) + cy) * 32u;
    const int rowB  = (int)(gbase * 256u) + l5 * 8;       // cell0 maps row
    const int mapsB = rowB - half * 256;                  // cell(2t-half) @t=0
    const int rlim  = rowB + 31 * 256;
    const unsigned gb = gbase * 4u;

    const char* MEc = (const char*)mean_map;
    const char* VAc = (const char*)var_map;
    const char* COc = (const char*)conf_map;
    char*       OMc = (char*)out_mean;
    char*       OVc = (char*)out_var;
    const float* kbp = kb_lds + (wave << 5);

    v4f inf[9];
    v4f H = (v4f)0.0f, Hp = (v4f)0.0f, recv = (v4f)0.0f, Rp = (v4f)0.0f;
    v2f mb[4], vb[4];
    float cb[4];

#define REDUCE(T0, T1)                                                  \
    v4f T0 = (v4f)0.0f, T1 = (v4f)0.0f;                                 \
    _Pragma("unroll")                                                   \
    for (int c = 0; c < 9; ++c) {                                       \
        T0 += inf[c] * ka.w0[c];                                        \
        if (IS_PLUS(c)) T1 += inf[c] * ka.w1[c];                        \
    }

#define SWAP32(DST, SRC)                                                \
    DST.x = __shfl_xor(SRC.x, 32, 64);                                  \
    DST.y = __shfl_xor(SRC.y, 32, 64);                                  \
    DST.z = __shfl_xor(SRC.z, 32, 64);                                  \
    DST.w = __shfl_xor(SRC.w, 32, 64);

#define FINSTORE(W, KB, MB, VB, CB, ADDR)                               \
    {                                                                   \
        float kb_  = (KB);                                              \
        float cf_  = (CB);                                              \
        float rin  = __builtin_amdgcn_rcpf(kb_ + EPSV);                 \
        float rden = __builtin_amdgcn_rcpf(cf_ + kb_ + EPSV);           \
        float scal = cf_ * kb_ * rden;                                  \
        float ya = (W).x * rin, yb = (W).z * rin;                       \
        float Sa = (W).y - 2.0f * ya * (W).x + ya * ya * kb_;           \
        float Sb = (W).w - 2.0f * yb * (W).z + yb * yb * kb_;           \
        float da = ya - (MB).x, db = yb - (MB).y;                       \
        v2f om, ov;                                                     \
        om.x = (cf_ * (MB).x + kb_ * ya) * rden;                        \
        om.y = (cf_ * (MB).y + kb_ * yb) * rden;                        \
        ov.x = (VB).x + Sa + scal * da * da;                            \
        ov.y = (VB).y + Sb + scal * db * db;                            \
        __builtin_nontemporal_store(om, (v2f*)(OMc + (ADDR)));          \
        __builtin_nontemporal_store(ov, (v2f*)(OVc + (ADDR)));          \
    }

#define MAPS_PF(SLOT, T)                                                \
    {                                                                   \
        int ro_ = min(mapsB + (T) * 512, rlim);                         \
        unsigned go_ = min(gb + (unsigned)((T) * 8 - half * 4),         \
                           gb + 124u);                                  \
        mb[SLOT] = __builtin_nontemporal_load((const v2f*)(MEc + ro_)); \
        vb[SLOT] = __builtin_nontemporal_load((const v2f*)(VAc + ro_)); \
        cb[SLOT] = *(const float*)(COc + go_);                          \
    }

    // ---- prologue: load pair 0; maps ring slots 0..3 ----
    #pragma unroll
    for (int c = 0; c < 9; ++c) {
        const char* p = (mk[c] & 3ull) ? tp[c] : sentp;
        inf[c] = *(const v4f*)(p + laneB);
    }
    // slot 0: cell-0 row for both halves (odd half never reads slot 0 at t=0)
    mb[0] = __builtin_nontemporal_load((const v2f*)(MEc + rowB));
    vb[0] = __builtin_nontemporal_load((const v2f*)(VAc + rowB));
    cb[0] = *(const float*)(COc + gb);
    MAPS_PF(1, 1)
    MAPS_PF(2, 2)
    MAPS_PF(3, 3)

    // ---- peel t = 0: even half finalizes cell 0 ----
    {
        REDUCE(t0, t1)
        #pragma unroll
        for (int c = 0; c < 9; ++c) {   // issue pair 1
            const char* p = ((mk[c] >> 2) & 3ull) ? tp[c] : sentp;
            inf[c] = *(const v4f*)(p + laneB + 1024);
        }
        SWAP32(recv, t1)
        H = t0 + recv;
        if (!half) {
            FINSTORE(H, kbp[0], mb[0], vb[0], cb[0], rowB)
        }
        Hp = H; Rp = recv;
        MAPS_PF(0, 4)                   // refill freed slot 0 (used at t=4)
    }

    // ---- main: t = 1..15 fully unrolled ----
    #pragma unroll
    for (int t = 1; t <= 15; ++t) {
        REDUCE(t0, t1)
        if (t < 15) {
            #pragma unroll
            for (int c = 0; c < 9; ++c) {   // issue pair t+1
                const char* p = ((mk[c] >> (2 * t + 2)) & 3ull) ? tp[c] : sentp;
                inf[c] = *(const v4f*)(p + laneB + (t + 1) * 1024);
            }
        }
        SWAP32(recv, t1)
        H = t0 + recv;
        // even: cell 2t = H + recv[t-1]; odd: cell 2t-1 = Hp + recv[t]
        v4f finv = half ? (Hp + recv) : (H + Rp);
        float kbv = kbp[2 * t - half];
        FINSTORE(finv, kbv, mb[t & 3], vb[t & 3], cb[t & 3], mapsB + t * 512)
        Hp = H; Rp = recv;
        if (t + 4 <= 16) {              // refill freed slot (used at t+4)
            MAPS_PF(t & 3, t + 4)
        }
    }

    // ---- epilogue t = 16: odd half finalizes cell 31 (slot 16&3 = 0) ----
    if (half) {
        FINSTORE(Hp, kbp[31], mb[0], vb[0], cb[0], mapsB + 16 * 512)
    }
#undef MAPS_PF
#undef FINSTORE
#undef SWAP32
#undef REDUCE
}

// ===========================================================================
// FALLBACK PATH (round-1 kernels, used only if workspace is too small)
// ===========================================================================
__global__ void lbki_accum(const float* __restrict__ pc,
                           float* __restrict__ y_sum,
                           float* __restrict__ sq_sum,
                           float* __restrict__ k_bar,
                           int npts) {
    __shared__ float kval_s[27];
    if (threadIdx.x < 27) kval_s[threadIdx.x] = kval_of(threadIdx.x);
    __syncthreads();

    int lane = threadIdx.x & 63;
    int wave = threadIdx.x >> 6;
    int p = blockIdx.x * (blockDim.x >> 6) + wave;
    if (p >= npts) return;

    const float* row = pc + (size_t)p * 67;
    int gx, gy, gz;
    base_cell(row, &gx, &gy, &gz);
    float f = row[3 + lane];
    float ff = f * f;

    #pragma unroll
    for (int o = 0; o < 27; ++o) {
        float kv = kval_s[o];
        if (kv <= 0.0f) continue;
        int nx = gx + (o / 9) - 1;
        int ny = gy + ((o / 3) % 3) - 1;
        int nz = gz + (o % 3) - 1;
        if ((unsigned)nx >= (unsigned)GXD) continue;
        if ((unsigned)ny >= (unsigned)GYD) continue;
        if ((unsigned)nz >= (unsigned)GZD) continue;
        size_t g = ((size_t)nx * GYD + ny) * GZD + nz;
        atomicAdd(&y_sum[g * DD + lane], kv * f);
        atomicAdd(&sq_sum[g * DD + lane], kv * ff);
        if (lane == 0) atomicAdd(&k_bar[g], kv);
    }
}

__global__ void lbki_finalize(const float* __restrict__ mean_map,
                              const float* __restrict__ var_map,
                              const float* __restrict__ conf_map,
                              float* __restrict__ out_mean,
                              float* __restrict__ out_var,
                              float* __restrict__ out_conf) {
    int lane = threadIdx.x & 63;
    int wave = threadIdx.x >> 6;
    int g = blockIdx.x * (blockDim.x >> 6) + wave;
    if (g >= GCELLS) return;

    float kb   = out_conf[g];
    float conf = conf_map[g];

    size_t idx = (size_t)g * DD + lane;
    float ys   = out_mean[idx];
    float sq   = out_var[idx];
    float mean = mean_map[idx];
    float var  = var_map[idx];

    float ybar  = ys / (kb + EPSV);
    float Sbar  = sq - 2.0f * ybar * ys + ybar * ybar * kb;
    float denom = conf + kb + EPSV;
    float dm    = ybar - mean;
    float scal  = conf * kb / denom;

    out_mean[idx] = (conf * mean + kb * ybar) / denom;
    out_var[idx]  = var + Sbar + scal * dm * dm;
    if (lane == 0) out_conf[g] = conf + kb;
}

// ===========================================================================
extern "C" void kernel_launch(void* const* d_in, const int* in_sizes, int n_in,
                              void* d_out, int out_size, void* d_ws, size_t ws_size,
                              hipStream_t stream) {
    const float* mean_map = (const float*)d_in[0];
    const float* var_map  = (const float*)d_in[1];
    const float* conf_map = (const float*)d_in[2];
    const float* pc       = (const float*)d_in[3];
    int npts = in_sizes[3] / 67;

    float* out      = (float*)d_out;
    float* out_mean = out;
    float* out_var  = out + (size_t)GCELLS * DD;
    float* out_conf = out + (size_t)2 * GCELLS * DD;

    const size_t M0_ELEMS = (size_t)GCELLS;
    const size_t MM_ELEMS = (size_t)GCELLS * 128 + 8192;   // + 32KB sentinel
    const size_t WS_NEEDED = (M0_ELEMS + MM_ELEMS) * sizeof(float);

    if (ws_size >= WS_NEEDED) {
        float* M0 = (float*)d_ws;
        float* MM = M0 + M0_ELEMS;

        // small zeroing only: counts (2MB) + sentinel pad (32KB)
        hipMemsetAsync(M0, 0, M0_ELEMS * sizeof(float), stream);
        hipMemsetAsync(MM + (size_t)GCELLS * 128, 0, 8192 * sizeof(float), stream);

        int wpb = 4;
        int pblocks = (npts + wpb - 1) / wpb;
        lbki_zero_rows<<<pblocks, 256, 0, stream>>>(pc, (float2*)MM, npts);
        lbki_build<<<pblocks, 256, 0, stream>>>(pc, M0, MM, npts);

        // host-side column weights (double precision, cast to f32)
        KvCols ka;
        for (int c = 0; c < 9; ++c) {
            int ox = c / 3 - 1, oy = c % 3 - 1;
            for (int k = 0; k < 2; ++k) {   // k = |oz|
                double dx = ox * (double)VOXX;
                double dy = oy * (double)VOXY;
                double dz = k  * (double)VOXZ;
                double d  = sqrt(dx * dx + dy * dy + dz * dz);
                double ang = 2.0 * (double)PIF * d / (double)ELL;
                double v = (1.0 / 3.0) * (2.0 + cos(ang)) * (1.0 - d / (double)ELL)
                         + (1.0 / (2.0 * (double)PIF)) * sin(ang);
                if (d >= (double)ELL) v = 0.0;
                v = v < 0.0 ? 0.0 : (v > 1.0 ? 1.0 : v);
                if (k == 0) ka.w0[c] = (float)v; else ka.w1[c] = (float)v;
            }
        }

        int sblocks = (GXD * GYD) / 8;   // 2048 blocks, % 8 == 0
        lbki_stencil_colB<<<sblocks, 512, 0, stream>>>(M0, MM,
                                                       mean_map, var_map, conf_map,
                                                       out_mean, out_var, out_conf,
                                                       ka);
    } else {
        hipMemsetAsync(d_out, 0, (size_t)out_size * sizeof(float), stream);
        int wpb = 4;
        int blocks = (npts + wpb - 1) / wpb;
        lbki_accum<<<blocks, 256, 0, stream>>>(pc, out_mean, out_var, out_conf, npts);
        int fblocks = GCELLS / 4;
        lbki_finalize<<<fblocks, 256, 0, stream>>>(mean_map, var_map, conf_map,
                                                   out_mean, out_var, out_conf);
    }
}

// Round 16
// 272.472 us; speedup vs baseline: 1.1324x; 1.1324x over previous
//
#include <hip/hip_runtime.h>
#include <math.h>

#define GXD 128
#define GYD 128
#define GZD 32
#define DD  64
#define GCELLS (GXD * GYD * GZD)   // 524288

#define MINX (-20.0f)
#define MINY (-20.0f)
#define MINZ (-2.0f)
#define VOXX (0.3125f)
#define VOXY (0.3125f)
#define VOXZ (0.25f)
#define ELL  (0.5f)
#define EPSV (1e-6f)
#define PIF  (3.14159265358979323846f)

typedef float v2f __attribute__((ext_vector_type(2)));
typedef float v4f __attribute__((ext_vector_type(4)));

// Column weights: for the 9 (ox,oy) columns, w0 = kval at oz=0, w1 = kval at
// |oz|=1. Corners (|ox|=|oy|=1) have w1 == 0 (d >= ELL). c = (ox+1)*3+(oy+1).
struct KvCols { float w0[9]; float w1[9]; };
#define IS_PLUS(c) ((c) == 1 || (c) == 3 || (c) == 4 || (c) == 5 || (c) == 7)

// ---------------------------------------------------------------------------
__device__ __forceinline__ float kval_of(int o) {   // fallback path only
    int ox = o / 9 - 1;
    int oy = (o / 3) % 3 - 1;
    int oz = o % 3 - 1;
    float dx = ox * VOXX, dy = oy * VOXY, dz = oz * VOXZ;
    float d = sqrtf(dx * dx + dy * dy + dz * dz);
    float ang = 2.0f * PIF * d / ELL;
    float v = (1.0f / 3.0f) * (2.0f + cosf(ang)) * (1.0f - d / ELL)
            + (1.0f / (2.0f * PIF)) * sinf(ang);
    v = (d >= ELL) ? 0.0f : v;
    return fminf(fmaxf(v, 0.0f), 1.0f);
}

__device__ __forceinline__ int base_cell(const float* __restrict__ row,
                                         int* cx, int* cy, int* cz) {
    float x = row[0], y = row[1], z = row[2];
    int gx = (int)floorf((x - MINX) / VOXX);
    int gy = (int)floorf((y - MINY) / VOXY);
    int gz = (int)floorf((z - MINZ) / VOXZ);
    gx = min(max(gx, 0), GXD - 1);
    gy = min(max(gy, 0), GYD - 1);
    gz = min(max(gz, 0), GZD - 1);
    *cx = gx; *cy = gy; *cz = gz;
    return (gx * GYD + gy) * GZD + gz;
}

// ===========================================================================
// FAST PATH — workspace (floats), FLAT layout (compact atomics):
//   M0 : [0, GCELLS)            cell counts (memset)
//   MM : [cell][feature][m1,m2] = 512B/cell; + 8192-float zero sentinel pad
// ===========================================================================

__global__ void lbki_zero_rows(const float* __restrict__ pc,
                               float2* __restrict__ MM2,
                               int npts) {
    int lane = threadIdx.x & 63;
    int wave = threadIdx.x >> 6;
    int p = blockIdx.x * (blockDim.x >> 6) + wave;
    if (p >= npts) return;
    int cx, cy, cz;
    int g = base_cell(pc + (size_t)p * 67, &cx, &cy, &cz);
    MM2[(size_t)g * DD + lane]       = make_float2(0.0f, 0.0f);
    MM2[(size_t)(g ^ 1) * DD + lane] = make_float2(0.0f, 0.0f);
}

__global__ void lbki_build(const float* __restrict__ pc,
                           float* __restrict__ M0,
                           float* __restrict__ MM,
                           int npts) {
    int lane = threadIdx.x & 63;
    int wave = threadIdx.x >> 6;
    int p = blockIdx.x * (blockDim.x >> 6) + wave;
    if (p >= npts) return;
    const float* row = pc + (size_t)p * 67;
    int cx, cy, cz;
    int g = base_cell(row, &cx, &cy, &cz);
    float f = row[3 + lane];
    size_t e = ((size_t)g * DD + lane) * 2;
    atomicAdd(&MM[e],     f);
    atomicAdd(&MM[e + 1], f * f);
    if (lane == 0) atomicAdd(&M0[g], 1.0f);
}

// z-column stencil fused with finalize. Block = 8 adjacent y-columns, one
// wave each; lanes 0-31 own even-z cells, 32-63 odd-z (flat-pair dwordx4).
// BLOCK-COOPERATIVE STAGING: each wave global-loads only its OWN-y 3 x-taps
// per pair-step (edge waves also the 2 y-halo columns) into double-buffered
// LDS; all 9 taps consumed via ds_read_b128. 30 pair-loads/block/step vs 72
// direct -> 2.4x gather traffic cut. Raw s_barrier + lgkmcnt keeps stage
// loads and maps in flight across barriers.
__global__ __launch_bounds__(512)
void lbki_stencil_colC(const float* __restrict__ M0,
                       const float* __restrict__ MM,
                       const float* __restrict__ mean_map,
                       const float* __restrict__ var_map,
                       const float* __restrict__ conf_map,
                       float* __restrict__ out_mean,
                       float* __restrict__ out_var,
                       float* __restrict__ out_conf,
                       KvCols ka) {
    __shared__ v4f      smPairs[2 * 30 * 64];  // 61440B: [buf][xo*10+yo][lane]
    __shared__ float    sm0[3 * 10 * 35];      // [xo][yo][zp], zp=z+1, pads 0
    __shared__ float    kb_lds[256];           // [col 0..7][z] k_bar
    __shared__ unsigned smask[30];             // per halo column occupancy
    const int tid  = threadIdx.x;
    const int lane = tid & 63;
    const int wave = __builtin_amdgcn_readfirstlane(tid >> 6);
    const int half = lane >> 5;
    const int l5   = lane & 31;

    // bijective XCD swizzle (2048 blocks, % 8 == 0)
    unsigned bid = blockIdx.x;
    unsigned chunk = gridDim.x >> 3;
    unsigned swz = (bid & 7u) * chunk + (bid >> 3);
    const int col0 = (int)(swz * 8u);
    const int cx  = col0 >> 7;
    const int cy0 = col0 & 127;

    // ---- stage M0 halo into LDS ----
    for (int e = tid; e < 3 * 10 * 35; e += 512) {
        int xo = e / 350;
        int r  = e - xo * 350;
        int yo = r / 35;
        int zp = r - yo * 35;
        int z  = zp - 1;
        int gx_ = cx - 1 + xo;
        int gy_ = cy0 - 1 + yo;
        bool v = ((unsigned)gx_ < (unsigned)GXD) &&
                 ((unsigned)gy_ < (unsigned)GYD) && ((unsigned)z < (unsigned)GZD);
        float val = 0.0f;
        if (v) val = M0[((gx_ << 7) + gy_) * 32 + z];
        sm0[e] = val;
    }
    __syncthreads();

    // ---- once per block: k_bar + out_conf + occupancy masks ----
    if (tid < 256) {
        int j = tid >> 5, z = tid & 31;
        float kb = 0.0f;
        #pragma unroll
        for (int c = 0; c < 9; ++c) {
            const float* sc = sm0 + ((c / 3) * 10 + j + c % 3) * 35 + z + 1;
            kb += ka.w0[c] * sc[0];
            if (IS_PLUS(c)) kb += ka.w1[c] * (sc[-1] + sc[1]);
        }
        kb_lds[(j << 5) + z] = kb;
        unsigned cell = (unsigned)((cx << 7) + cy0 + j) * 32u + (unsigned)z;
        out_conf[cell] = conf_map[cell] + kb;
    } else if (tid < 256 + 30) {
        int idx = tid - 256;
        const float* sc = sm0 + idx * 35 + 1;
        unsigned m = 0;
        for (int z = 0; z < 32; ++z)
            if (sc[z] != 0.0f) m |= (1u << z);
        smask[idx] = m;
    }
    __syncthreads();

    // ---- per-wave staging setup (wave-uniform -> SGPR) ----
    const int cy = cy0 + wave;
    const char* sentp = (const char*)MM + (size_t)GCELLS * 512u;  // 32KB pad

    // own-y taps (3): column (cx+x-1, cy)
    unsigned mkO[3]; const char* tpO[3];
    #pragma unroll
    for (int x = 0; x < 3; ++x) {
        mkO[x] = (unsigned)__builtin_amdgcn_readfirstlane(
                     (int)smask[x * 10 + wave + 1]);
        int nx = cx + x - 1;
        bool v = ((unsigned)nx < (unsigned)GXD);
        tpO[x] = v ? ((const char*)MM + (size_t)(((nx << 7) + cy) << 5) * 512u)
                   : sentp;
    }
    // y-halo taps for edge waves: wave0 -> yo=0 (cy0-1), wave7 -> yo=9 (cy0+8)
    const bool haloW = (wave == 0) || (wave == 7);
    const int  hyo   = (wave == 0) ? 0 : 9;
    const int  hy    = cy0 - 1 + hyo;
    unsigned mkH[3]; const char* tpH[3];
    #pragma unroll
    for (int x = 0; x < 3; ++x) {
        mkH[x] = (unsigned)__builtin_amdgcn_readfirstlane(
                     (int)smask[x * 10 + hyo]);
        int nx = cx + x - 1;
        bool v = ((unsigned)nx < (unsigned)GXD) && ((unsigned)hy < (unsigned)GYD);
        tpH[x] = v ? ((const char*)MM + (size_t)(((nx << 7) + hy) << 5) * 512u)
                   : sentp;
    }
    const int laneB = lane * 16;

    // LDS bases (imm offsets carry buf/x/c selects)
    v4f* tapBase = &smPairs[(wave) * 64 + lane];       // +((c/3)*10+c%3)*64
    v4f* wrBase  = &smPairs[(wave + 1) * 64 + lane];   // own-y write
    v4f* hwBase  = &smPairs[hyo * 64 + lane];          // halo write

    const unsigned gbase = (unsigned)((cx << 7) + cy) * 32u;
    const int rowB  = (int)(gbase * 256u) + l5 * 8;
    const int mapsB = rowB - half * 256;
    const unsigned gb = gbase * 4u;

    const char* MEc = (const char*)mean_map;
    const char* VAc = (const char*)var_map;
    const char* COc = (const char*)conf_map;
    char*       OMc = (char*)out_mean;
    char*       OVc = (char*)out_var;
    const float* kbp = kb_lds + (wave << 5);

    v4f inf[9];
    v4f H = (v4f)0.0f, Hp = (v4f)0.0f, recv = (v4f)0.0f, Rp = (v4f)0.0f;
    v4f rA[3], rH[3];
    rH[0] = rH[1] = rH[2] = (v4f)0.0f;
    v2f mb[2], vb[2];
    float cb[2];

#define REDUCE(T0, T1)                                                  \
    v4f T0 = (v4f)0.0f, T1 = (v4f)0.0f;                                 \
    _Pragma("unroll")                                                   \
    for (int c = 0; c < 9; ++c) {                                       \
        T0 += inf[c] * ka.w0[c];                                        \
        if (IS_PLUS(c)) T1 += inf[c] * ka.w1[c];                        \
    }

#define SWAP32(DST, SRC)                                                \
    DST.x = __shfl_xor(SRC.x, 32, 64);                                  \
    DST.y = __shfl_xor(SRC.y, 32, 64);                                  \
    DST.z = __shfl_xor(SRC.z, 32, 64);                                  \
    DST.w = __shfl_xor(SRC.w, 32, 64);

#define FINSTORE(W, KB, MB, VB, CB, ADDR)                               \
    {                                                                   \
        float kb_  = (KB);                                              \
        float cf_  = (CB);                                              \
        float rin  = __builtin_amdgcn_rcpf(kb_ + EPSV);                 \
        float rden = __builtin_amdgcn_rcpf(cf_ + kb_ + EPSV);           \
        float scal = cf_ * kb_ * rden;                                  \
        float ya = (W).x * rin, yb = (W).z * rin;                       \
        float Sa = (W).y - 2.0f * ya * (W).x + ya * ya * kb_;           \
        float Sb = (W).w - 2.0f * yb * (W).z + yb * yb * kb_;           \
        float da = ya - (MB).x, db = yb - (MB).y;                       \
        v2f om, ov;                                                     \
        om.x = (cf_ * (MB).x + kb_ * ya) * rden;                        \
        om.y = (cf_ * (MB).y + kb_ * yb) * rden;                        \
        ov.x = (VB).x + Sa + scal * da * da;                            \
        ov.y = (VB).y + Sb + scal * db * db;                            \
        __builtin_nontemporal_store(om, (v2f*)(OMc + (ADDR)));          \
        __builtin_nontemporal_store(ov, (v2f*)(OVc + (ADDR)));          \
    }

#define TAPS_READ(BUF)                                                  \
    _Pragma("unroll")                                                   \
    for (int c = 0; c < 9; ++c)                                         \
        inf[c] = tapBase[(BUF) * 1920 + ((c / 3) * 10 + (c % 3)) * 64];

#define STAGE_ISSUE(SHIFT, TOFF)                                        \
    _Pragma("unroll")                                                   \
    for (int x = 0; x < 3; ++x) {                                       \
        const char* p_ = ((mkO[x] >> (SHIFT)) & 3u) ? tpO[x] : sentp;   \
        rA[x] = *(const v4f*)(p_ + laneB + (TOFF) * 1024);              \
    }                                                                   \
    if (haloW) {                                                        \
        _Pragma("unroll")                                               \
        for (int x = 0; x < 3; ++x) {                                   \
            const char* p_ = ((mkH[x] >> (SHIFT)) & 3u) ? tpH[x] : sentp; \
            rH[x] = *(const v4f*)(p_ + laneB + (TOFF) * 1024);          \
        }                                                               \
    }

#define STAGE_WRITE(BUF)                                                \
    _Pragma("unroll")                                                   \
    for (int x = 0; x < 3; ++x)                                         \
        wrBase[(BUF) * 1920 + x * 640] = rA[x];                         \
    if (haloW) {                                                        \
        _Pragma("unroll")                                               \
        for (int x = 0; x < 3; ++x)                                     \
            hwBase[(BUF) * 1920 + x * 640] = rH[x];                     \
    }

#define BARRIER                                                         \
    asm volatile("s_waitcnt lgkmcnt(0)" ::: "memory");                  \
    __builtin_amdgcn_s_barrier();                                       \
    asm volatile("" ::: "memory");

    // ---- prologue: stage pair 0 -> buf0; issue pair 1; maps slots 0,1 ----
    STAGE_ISSUE(0, 0)
    STAGE_WRITE(0)
    STAGE_ISSUE(2, 1)
    mb[0] = __builtin_nontemporal_load((const v2f*)(MEc + rowB));
    vb[0] = __builtin_nontemporal_load((const v2f*)(VAc + rowB));
    cb[0] = *(const float*)(COc + gb);
    mb[1] = __builtin_nontemporal_load((const v2f*)(MEc + mapsB + 512));
    vb[1] = __builtin_nontemporal_load((const v2f*)(VAc + mapsB + 512));
    cb[1] = *(const float*)(COc + gb + 8 - half * 4);
    BARRIER

    // ---- peel t = 0: even half finalizes cell 0 ----
    {
        TAPS_READ(0)
        REDUCE(t0, t1)
        STAGE_WRITE(1)              // pair 1 -> buf1
        STAGE_ISSUE(4, 2)           // pair 2 -> rA
        SWAP32(recv, t1)
        H = t0 + recv;
        if (!half) {
            FINSTORE(H, kbp[0], mb[0], vb[0], cb[0], rowB)
        }
        Hp = H; Rp = recv;
        // maps t=2 -> slot0
        mb[0] = __builtin_nontemporal_load((const v2f*)(MEc + mapsB + 1024));
        vb[0] = __builtin_nontemporal_load((const v2f*)(VAc + mapsB + 1024));
        cb[0] = *(const float*)(COc + gb + 16 - half * 4);
        BARRIER
    }

    // ---- main: t = 1..15 fully unrolled ----
    #pragma unroll
    for (int t = 1; t <= 15; ++t) {
        TAPS_READ(t & 1)
        REDUCE(t0, t1)
        if (t < 15) {
            STAGE_WRITE((t + 1) & 1)           // pair t+1
            if (t < 14) {
                STAGE_ISSUE(2 * t + 4, t + 2)  // pair t+2
            }
        }
        SWAP32(recv, t1)
        H = t0 + recv;
        // even: cell 2t = H + recv[t-1]; odd: cell 2t-1 = Hp + recv[t]
        v4f finv = half ? (Hp + recv) : (H + Rp);
        float kbv = kbp[2 * t - half];
        FINSTORE(finv, kbv, mb[t & 1], vb[t & 1], cb[t & 1], mapsB + t * 512)
        Hp = H; Rp = recv;
        if (t < 15) {   // maps t+1 -> slot (t+1)&1
            mb[(t + 1) & 1] = __builtin_nontemporal_load((const v2f*)(MEc + mapsB + (t + 1) * 512));
            vb[(t + 1) & 1] = __builtin_nontemporal_load((const v2f*)(VAc + mapsB + (t + 1) * 512));
            cb[(t + 1) & 1] = *(const float*)(COc + gb + (t + 1) * 8 - half * 4);
            BARRIER
        } else {        // maps t=16 (clamped; only odd half's value used)
            int a16 = min(mapsB + 16 * 512, rowB + 31 * 256);
            mb[0] = __builtin_nontemporal_load((const v2f*)(MEc + a16));
            vb[0] = __builtin_nontemporal_load((const v2f*)(VAc + a16));
            cb[0] = *(const float*)(COc + min(gb + 128u - (unsigned)(half * 4), gb + 124u));
        }
    }

    // ---- epilogue t = 16: odd half finalizes cell 31 ----
    if (half) {
        FINSTORE(Hp, kbp[31], mb[0], vb[0], cb[0], mapsB + 16 * 512)
    }
#undef BARRIER
#undef STAGE_WRITE
#undef STAGE_ISSUE
#undef TAPS_READ
#undef FINSTORE
#undef SWAP32
#undef REDUCE
}

// ===========================================================================
// FALLBACK PATH (round-1 kernels, used only if workspace is too small)
// ===========================================================================
__global__ void lbki_accum(const float* __restrict__ pc,
                           float* __restrict__ y_sum,
                           float* __restrict__ sq_sum,
                           float* __restrict__ k_bar,
                           int npts) {
    __shared__ float kval_s[27];
    if (threadIdx.x < 27) kval_s[threadIdx.x] = kval_of(threadIdx.x);
    __syncthreads();

    int lane = threadIdx.x & 63;
    int wave = threadIdx.x >> 6;
    int p = blockIdx.x * (blockDim.x >> 6) + wave;
    if (p >= npts) return;

    const float* row = pc + (size_t)p * 67;
    int gx, gy, gz;
    base_cell(row, &gx, &gy, &gz);
    float f = row[3 + lane];
    float ff = f * f;

    #pragma unroll
    for (int o = 0; o < 27; ++o) {
        float kv = kval_s[o];
        if (kv <= 0.0f) continue;
        int nx = gx + (o / 9) - 1;
        int ny = gy + ((o / 3) % 3) - 1;
        int nz = gz + (o % 3) - 1;
        if ((unsigned)nx >= (unsigned)GXD) continue;
        if ((unsigned)ny >= (unsigned)GYD) continue;
        if ((unsigned)nz >= (unsigned)GZD) continue;
        size_t g = ((size_t)nx * GYD + ny) * GZD + nz;
        atomicAdd(&y_sum[g * DD + lane], kv * f);
        atomicAdd(&sq_sum[g * DD + lane], kv * ff);
        if (lane == 0) atomicAdd(&k_bar[g], kv);
    }
}

__global__ void lbki_finalize(const float* __restrict__ mean_map,
                              const float* __restrict__ var_map,
                              const float* __restrict__ conf_map,
                              float* __restrict__ out_mean,
                              float* __restrict__ out_var,
                              float* __restrict__ out_conf) {
    int lane = threadIdx.x & 63;
    int wave = threadIdx.x >> 6;
    int g = blockIdx.x * (blockDim.x >> 6) + wave;
    if (g >= GCELLS) return;

    float kb   = out_conf[g];
    float conf = conf_map[g];

    size_t idx = (size_t)g * DD + lane;
    float ys   = out_mean[idx];
    float sq   = out_var[idx];
    float mean = mean_map[idx];
    float var  = var_map[idx];

    float ybar  = ys / (kb + EPSV);
    float Sbar  = sq - 2.0f * ybar * ys + ybar * ybar * kb;
    float denom = conf + kb + EPSV;
    float dm    = ybar - mean;
    float scal  = conf * kb / denom;

    out_mean[idx] = (conf * mean + kb * ybar) / denom;
    out_var[idx]  = var + Sbar + scal * dm * dm;
    if (lane == 0) out_conf[g] = conf + kb;
}

// ===========================================================================
extern "C" void kernel_launch(void* const* d_in, const int* in_sizes, int n_in,
                              void* d_out, int out_size, void* d_ws, size_t ws_size,
                              hipStream_t stream) {
    const float* mean_map = (const float*)d_in[0];
    const float* var_map  = (const float*)d_in[1];
    const float* conf_map = (const float*)d_in[2];
    const float* pc       = (const float*)d_in[3];
    int npts = in_sizes[3] / 67;

    float* out      = (float*)d_out;
    float* out_mean = out;
    float* out_var  = out + (size_t)GCELLS * DD;
    float* out_conf = out + (size_t)2 * GCELLS * DD;

    const size_t M0_ELEMS = (size_t)GCELLS;
    const size_t MM_ELEMS = (size_t)GCELLS * 128 + 8192;   // + 32KB sentinel
    const size_t WS_NEEDED = (M0_ELEMS + MM_ELEMS) * sizeof(float);

    if (ws_size >= WS_NEEDED) {
        float* M0 = (float*)d_ws;
        float* MM = M0 + M0_ELEMS;

        // small zeroing only: counts (2MB) + sentinel pad (32KB)
        hipMemsetAsync(M0, 0, M0_ELEMS * sizeof(float), stream);
        hipMemsetAsync(MM + (size_t)GCELLS * 128, 0, 8192 * sizeof(float), stream);

        int wpb = 4;
        int pblocks = (npts + wpb - 1) / wpb;
        lbki_zero_rows<<<pblocks, 256, 0, stream>>>(pc, (float2*)MM, npts);
        lbki_build<<<pblocks, 256, 0, stream>>>(pc, M0, MM, npts);

        // host-side column weights (double precision, cast to f32)
        KvCols ka;
        for (int c = 0; c < 9; ++c) {
            int ox = c / 3 - 1, oy = c % 3 - 1;
            for (int k = 0; k < 2; ++k) {   // k = |oz|
                double dx = ox * (double)VOXX;
                double dy = oy * (double)VOXY;
                double dz = k  * (double)VOXZ;
                double d  = sqrt(dx * dx + dy * dy + dz * dz);
                double ang = 2.0 * (double)PIF * d / (double)ELL;
                double v = (1.0 / 3.0) * (2.0 + cos(ang)) * (1.0 - d / (double)ELL)
                         + (1.0 / (2.0 * (double)PIF)) * sin(ang);
                if (d >= (double)ELL) v = 0.0;
                v = v < 0.0 ? 0.0 : (v > 1.0 ? 1.0 : v);
                if (k == 0) ka.w0[c] = (float)v; else ka.w1[c] = (float)v;
            }
        }

        int sblocks = (GXD * GYD) / 8;   // 2048 blocks, % 8 == 0
        lbki_stencil_colC<<<sblocks, 512, 0, stream>>>(M0, MM,
                                                       mean_map, var_map, conf_map,
                                                       out_mean, out_var, out_conf,
                                                       ka);
    } else {
        hipMemsetAsync(d_out, 0, (size_t)out_size * sizeof(float), stream);
        int wpb = 4;
        int blocks = (npts + wpb - 1) / wpb;
        lbki_accum<<<blocks, 256, 0, stream>>>(pc, out_mean, out_var, out_conf, npts);
        int fblocks = GCELLS / 4;
        lbki_finalize<<<fblocks, 256, 0, stream>>>(mean_map, var_map, conf_map,
                                                   out_mean, out_var, out_conf);
    }
}

// Round 17
// 257.239 us; speedup vs baseline: 1.1995x; 1.0592x over previous
//
#include <hip/hip_runtime.h>
#include <math.h>

#define GXD 128
#define GYD 128
#define GZD 32
#define DD  64
#define GCELLS (GXD * GYD * GZD)   // 524288

#define MINX (-20.0f)
#define MINY (-20.0f)
#define MINZ (-2.0f)
#define VOXX (0.3125f)
#define VOXY (0.3125f)
#define VOXZ (0.25f)
#define ELL  (0.5f)
#define EPSV (1e-6f)
#define PIF  (3.14159265358979323846f)

typedef float v2f __attribute__((ext_vector_type(2)));
typedef float v4f __attribute__((ext_vector_type(4)));

// Column weights: for the 9 (ox,oy) columns, w0 = kval at oz=0, w1 = kval at
// |oz|=1. Corners (|ox|=|oy|=1) have w1 == 0 (d >= ELL). c = (ox+1)*3+(oy+1).
struct KvCols { float w0[9]; float w1[9]; };
#define IS_PLUS(c) ((c) == 1 || (c) == 3 || (c) == 4 || (c) == 5 || (c) == 7)

// ---------------------------------------------------------------------------
__device__ __forceinline__ float kval_of(int o) {   // fallback path only
    int ox = o / 9 - 1;
    int oy = (o / 3) % 3 - 1;
    int oz = o % 3 - 1;
    float dx = ox * VOXX, dy = oy * VOXY, dz = oz * VOXZ;
    float d = sqrtf(dx * dx + dy * dy + dz * dz);
    float ang = 2.0f * PIF * d / ELL;
    float v = (1.0f / 3.0f) * (2.0f + cosf(ang)) * (1.0f - d / ELL)
            + (1.0f / (2.0f * PIF)) * sinf(ang);
    v = (d >= ELL) ? 0.0f : v;
    return fminf(fmaxf(v, 0.0f), 1.0f);
}

__device__ __forceinline__ int base_cell(const float* __restrict__ row,
                                         int* cx, int* cy, int* cz) {
    float x = row[0], y = row[1], z = row[2];
    int gx = (int)floorf((x - MINX) / VOXX);
    int gy = (int)floorf((y - MINY) / VOXY);
    int gz = (int)floorf((z - MINZ) / VOXZ);
    gx = min(max(gx, 0), GXD - 1);
    gy = min(max(gy, 0), GYD - 1);
    gz = min(max(gz, 0), GZD - 1);
    *cx = gx; *cy = gy; *cz = gz;
    return (gx * GYD + gy) * GZD + gz;
}

// ===========================================================================
// FAST PATH — workspace (floats), FLAT layout:
//   M0 : [0, GCELLS)            cell counts (memset — the only memset)
//   MM : [cell][feature][m1,m2] = 512B/cell. NO sentinel zeroing needed:
//        stage-write masking zeroes empty/garbage halves; the "sentinel"
//        pointer is just MM itself (address safety only).
// ===========================================================================

// Pass 1: zero ONLY the point's own cell row (partner garbage is masked at
// staging). Races benign: everyone writes zeros, before build.
__global__ void lbki_zero_rows(const float* __restrict__ pc,
                               float2* __restrict__ MM2,
                               int npts) {
    int lane = threadIdx.x & 63;
    int wave = threadIdx.x >> 6;
    int p = blockIdx.x * (blockDim.x >> 6) + wave;
    if (p >= npts) return;
    int cx, cy, cz;
    int g = base_cell(pc + (size_t)p * 67, &cx, &cy, &cz);
    MM2[(size_t)g * DD + lane] = make_float2(0.0f, 0.0f);
}

// Pass 2: compact scatter (8B stride per lane)
__global__ void lbki_build(const float* __restrict__ pc,
                           float* __restrict__ M0,
                           float* __restrict__ MM,
                           int npts) {
    int lane = threadIdx.x & 63;
    int wave = threadIdx.x >> 6;
    int p = blockIdx.x * (blockDim.x >> 6) + wave;
    if (p >= npts) return;
    const float* row = pc + (size_t)p * 67;
    int cx, cy, cz;
    int g = base_cell(row, &cx, &cy, &cz);
    float f = row[3 + lane];
    size_t e = ((size_t)g * DD + lane) * 2;
    atomicAdd(&MM[e],     f);
    atomicAdd(&MM[e + 1], f * f);
    if (lane == 0) atomicAdd(&M0[g], 1.0f);
}

// z-column stencil fused with finalize. Block = 8 adjacent y-columns, one
// wave each; lanes 0-31 own even-z cells, 32-63 odd-z (flat-pair dwordx4).
// BLOCK-COOPERATIVE STAGING, BALANCED: each wave loads its 3 own-y x-taps;
// the 6 y-halo columns are spread one each over waves 1..6 (max 4 loads/wave
// per step, no edge-wave convoy). Per-cell occupancy MASKING at STAGE_WRITE
// zeroes garbage halves (replaces partner-row zeroing). Raw s_barrier +
// lgkmcnt keeps stage loads and maps in flight across barriers.
__global__ __launch_bounds__(512)
void lbki_stencil_colD(const float* __restrict__ M0,
                       const float* __restrict__ MM,
                       const float* __restrict__ mean_map,
                       const float* __restrict__ var_map,
                       const float* __restrict__ conf_map,
                       float* __restrict__ out_mean,
                       float* __restrict__ out_var,
                       float* __restrict__ out_conf,
                       KvCols ka) {
    __shared__ v4f      smPairs[2 * 30 * 64];  // 61440B: [buf][xo*10+yo][lane]
    __shared__ float    sm0[3 * 10 * 35];      // [xo][yo][zp], zp=z+1, pads 0
    __shared__ float    kb_lds[256];           // [col 0..7][z] k_bar
    __shared__ unsigned smask[30];             // per halo column occupancy
    const int tid  = threadIdx.x;
    const int lane = tid & 63;
    const int wave = __builtin_amdgcn_readfirstlane(tid >> 6);
    const int half = lane >> 5;
    const int l5   = lane & 31;

    // bijective XCD swizzle (2048 blocks, % 8 == 0)
    unsigned bid = blockIdx.x;
    unsigned chunk = gridDim.x >> 3;
    unsigned swz = (bid & 7u) * chunk + (bid >> 3);
    const int col0 = (int)(swz * 8u);
    const int cx  = col0 >> 7;
    const int cy0 = col0 & 127;

    // ---- stage M0 halo into LDS ----
    for (int e = tid; e < 3 * 10 * 35; e += 512) {
        int xo = e / 350;
        int r  = e - xo * 350;
        int yo = r / 35;
        int zp = r - yo * 35;
        int z  = zp - 1;
        int gx_ = cx - 1 + xo;
        int gy_ = cy0 - 1 + yo;
        bool v = ((unsigned)gx_ < (unsigned)GXD) &&
                 ((unsigned)gy_ < (unsigned)GYD) && ((unsigned)z < (unsigned)GZD);
        float val = 0.0f;
        if (v) val = M0[((gx_ << 7) + gy_) * 32 + z];
        sm0[e] = val;
    }
    __syncthreads();

    // ---- once per block: k_bar + out_conf + occupancy masks ----
    if (tid < 256) {
        int j = tid >> 5, z = tid & 31;
        float kb = 0.0f;
        #pragma unroll
        for (int c = 0; c < 9; ++c) {
            const float* sc = sm0 + ((c / 3) * 10 + j + c % 3) * 35 + z + 1;
            kb += ka.w0[c] * sc[0];
            if (IS_PLUS(c)) kb += ka.w1[c] * (sc[-1] + sc[1]);
        }
        kb_lds[(j << 5) + z] = kb;
        unsigned cell = (unsigned)((cx << 7) + cy0 + j) * 32u + (unsigned)z;
        out_conf[cell] = conf_map[cell] + kb;
    } else if (tid < 256 + 30) {
        int idx = tid - 256;
        const float* sc = sm0 + idx * 35 + 1;
        unsigned m = 0;
        for (int z = 0; z < 32; ++z)
            if (sc[z] != 0.0f) m |= (1u << z);
        smask[idx] = m;
    }
    __syncthreads();

    // ---- per-wave staging setup (wave-uniform -> SGPR) ----
    const int cy = cy0 + wave;
    const char* sentp = (const char*)MM;   // address-safety only (masked out)

    // own-y taps (3): column (cx+x-1, cy)
    unsigned mkO[3]; const char* tpO[3];
    #pragma unroll
    for (int x = 0; x < 3; ++x) {
        mkO[x] = (unsigned)__builtin_amdgcn_readfirstlane(
                     (int)smask[x * 10 + wave + 1]);
        int nx = cx + x - 1;
        bool v = ((unsigned)nx < (unsigned)GXD);
        tpO[x] = v ? ((const char*)MM + (size_t)(((nx << 7) + cy) << 5) * 512u)
                   : sentp;
    }
    // balanced halo: wave w in 1..6 stages halo combo w-1
    // combo = hyo_sel*3 + hx ; hyo_sel 0 -> yo=0 (cy0-1), 1 -> yo=9 (cy0+8)
    const bool haloW = (wave >= 1) && (wave <= 6);
    const int combo  = haloW ? (wave - 1) : 0;
    const int hx     = combo % 3;
    const int hyo    = (combo / 3) ? 9 : 0;
    const int hy     = cy0 - 1 + hyo;
    unsigned mkH = (unsigned)__builtin_amdgcn_readfirstlane(
                       (int)smask[hx * 10 + hyo]);
    int hnx = cx + hx - 1;
    bool hv = ((unsigned)hnx < (unsigned)GXD) && ((unsigned)hy < (unsigned)GYD);
    const char* tpH = hv ? ((const char*)MM +
                            (size_t)(((hnx << 7) + hy) << 5) * 512u)
                         : sentp;

    const int laneB = lane * 16;

    // LDS bases
    v4f* tapBase = &smPairs[(wave) * 64 + lane];        // +((c/3)*10+c%3)*64
    v4f* wrBase  = &smPairs[(wave + 1) * 64 + lane];    // own-y write
    v4f* hwPtr   = &smPairs[(hx * 10 + hyo) * 64 + lane];  // halo write

    const unsigned gbase = (unsigned)((cx << 7) + cy) * 32u;
    const int rowB  = (int)(gbase * 256u) + l5 * 8;
    const int mapsB = rowB - half * 256;
    const unsigned gb = gbase * 4u;

    const char* MEc = (const char*)mean_map;
    const char* VAc = (const char*)var_map;
    const char* COc = (const char*)conf_map;
    char*       OMc = (char*)out_mean;
    char*       OVc = (char*)out_var;
    const float* kbp = kb_lds + (wave << 5);

    v4f inf[9];
    v4f H = (v4f)0.0f, Hp = (v4f)0.0f, recv = (v4f)0.0f, Rp = (v4f)0.0f;
    v4f rA[3], rH;
    rH = (v4f)0.0f;
    v2f mb[2], vb[2];
    float cb[2];

#define REDUCE(T0, T1)                                                  \
    v4f T0 = (v4f)0.0f, T1 = (v4f)0.0f;                                 \
    _Pragma("unroll")                                                   \
    for (int c = 0; c < 9; ++c) {                                       \
        T0 += inf[c] * ka.w0[c];                                        \
        if (IS_PLUS(c)) T1 += inf[c] * ka.w1[c];                        \
    }

#define SWAP32(DST, SRC)                                                \
    DST.x = __shfl_xor(SRC.x, 32, 64);                                  \
    DST.y = __shfl_xor(SRC.y, 32, 64);                                  \
    DST.z = __shfl_xor(SRC.z, 32, 64);                                  \
    DST.w = __shfl_xor(SRC.w, 32, 64);

#define FINSTORE(W, KB, MB, VB, CB, ADDR)                               \
    {                                                                   \
        float kb_  = (KB);                                              \
        float cf_  = (CB);                                              \
        float rin  = __builtin_amdgcn_rcpf(kb_ + EPSV);                 \
        float rden = __builtin_amdgcn_rcpf(cf_ + kb_ + EPSV);           \
        float scal = cf_ * kb_ * rden;                                  \
        float ya = (W).x * rin, yb = (W).z * rin;                       \
        float Sa = (W).y - 2.0f * ya * (W).x + ya * ya * kb_;           \
        float Sb = (W).w - 2.0f * yb * (W).z + yb * yb * kb_;           \
        float da = ya - (MB).x, db = yb - (MB).y;                       \
        v2f om, ov;                                                     \
        om.x = (cf_ * (MB).x + kb_ * ya) * rden;                        \
        om.y = (cf_ * (MB).y + kb_ * yb) * rden;                        \
        ov.x = (VB).x + Sa + scal * da * da;                            \
        ov.y = (VB).y + Sb + scal * db * db;                            \
        __builtin_nontemporal_store(om, (v2f*)(OMc + (ADDR)));          \
        __builtin_nontemporal_store(ov, (v2f*)(OVc + (ADDR)));          \
    }

#define TAPS_READ(BUF)                                                  \
    _Pragma("unroll")                                                   \
    for (int c = 0; c < 9; ++c)                                         \
        inf[c] = tapBase[(BUF) * 1920 + ((c / 3) * 10 + (c % 3)) * 64];

// issue only (no use of loaded regs -> loads stay in flight)
#define STAGE_ISSUE(SHIFT, TOFF)                                        \
    _Pragma("unroll")                                                   \
    for (int x = 0; x < 3; ++x) {                                       \
        const char* p_ = ((mkO[x] >> (SHIFT)) & 3u) ? tpO[x] : sentp;   \
        rA[x] = *(const v4f*)(p_ + laneB + (TOFF) * 1024);              \
    }                                                                   \
    if (haloW) {                                                        \
        const char* p_ = ((mkH >> (SHIFT)) & 3u) ? tpH : sentp;         \
        rH = *(const v4f*)(p_ + laneB + (TOFF) * 1024);                 \
    }

// write with per-half occupancy masking (SH = shift of the written pair)
#define STAGE_WRITE(BUF, SH)                                            \
    _Pragma("unroll")                                                   \
    for (int x = 0; x < 3; ++x) {                                       \
        unsigned b_ = (mkO[x] >> (SH)) & 3u;                            \
        bool keep_ = (half ? (b_ & 2u) : (b_ & 1u)) != 0u;              \
        wrBase[(BUF) * 1920 + x * 640] = keep_ ? rA[x] : (v4f)0.0f;     \
    }                                                                   \
    if (haloW) {                                                        \
        unsigned b_ = (mkH >> (SH)) & 3u;                               \
        bool keep_ = (half ? (b_ & 2u) : (b_ & 1u)) != 0u;              \
        hwPtr[(BUF) * 1920] = keep_ ? rH : (v4f)0.0f;                   \
    }

#define BARRIER                                                         \
    asm volatile("s_waitcnt lgkmcnt(0)" ::: "memory");                  \
    __builtin_amdgcn_s_barrier();                                       \
    asm volatile("" ::: "memory");

    // ---- prologue: stage pair 0 -> buf0; issue pair 1; maps slots 0,1 ----
    STAGE_ISSUE(0, 0)
    STAGE_WRITE(0, 0)
    STAGE_ISSUE(2, 1)
    mb[0] = __builtin_nontemporal_load((const v2f*)(MEc + rowB));
    vb[0] = __builtin_nontemporal_load((const v2f*)(VAc + rowB));
    cb[0] = *(const float*)(COc + gb);
    mb[1] = __builtin_nontemporal_load((const v2f*)(MEc + mapsB + 512));
    vb[1] = __builtin_nontemporal_load((const v2f*)(VAc + mapsB + 512));
    cb[1] = *(const float*)(COc + gb + 8 - half * 4);
    BARRIER

    // ---- peel t = 0: even half finalizes cell 0 ----
    {
        TAPS_READ(0)
        REDUCE(t0, t1)
        STAGE_WRITE(1, 2)           // pair 1 -> buf1 (issued with shift 2)
        STAGE_ISSUE(4, 2)           // pair 2 -> rA/rH
        SWAP32(recv, t1)
        H = t0 + recv;
        if (!half) {
            FINSTORE(H, kbp[0], mb[0], vb[0], cb[0], rowB)
        }
        Hp = H; Rp = recv;
        // maps t=2 -> slot0
        mb[0] = __builtin_nontemporal_load((const v2f*)(MEc + mapsB + 1024));
        vb[0] = __builtin_nontemporal_load((const v2f*)(VAc + mapsB + 1024));
        cb[0] = *(const float*)(COc + gb + 16 - half * 4);
        BARRIER
    }

    // ---- main: t = 1..15 fully unrolled ----
    #pragma unroll
    for (int t = 1; t <= 15; ++t) {
        TAPS_READ(t & 1)
        REDUCE(t0, t1)
        if (t < 15) {
            STAGE_WRITE((t + 1) & 1, 2 * t + 2)   // pair t+1
            if (t < 14) {
                STAGE_ISSUE(2 * t + 4, t + 2)     // pair t+2
            }
        }
        SWAP32(recv, t1)
        H = t0 + recv;
        // even: cell 2t = H + recv[t-1]; odd: cell 2t-1 = Hp + recv[t]
        v4f finv = half ? (Hp + recv) : (H + Rp);
        float kbv = kbp[2 * t - half];
        FINSTORE(finv, kbv, mb[t & 1], vb[t & 1], cb[t & 1], mapsB + t * 512)
        Hp = H; Rp = recv;
        if (t < 15) {   // maps t+1 -> slot (t+1)&1
            mb[(t + 1) & 1] = __builtin_nontemporal_load((const v2f*)(MEc + mapsB + (t + 1) * 512));
            vb[(t + 1) & 1] = __builtin_nontemporal_load((const v2f*)(VAc + mapsB + (t + 1) * 512));
            cb[(t + 1) & 1] = *(const float*)(COc + gb + (t + 1) * 8 - half * 4);
            BARRIER
        } else {        // maps t=16 (clamped; only odd half's value used)
            int a16 = min(mapsB + 16 * 512, rowB + 31 * 256);
            mb[0] = __builtin_nontemporal_load((const v2f*)(MEc + a16));
            vb[0] = __builtin_nontemporal_load((const v2f*)(VAc + a16));
            cb[0] = *(const float*)(COc + min(gb + 128u - (unsigned)(half * 4), gb + 124u));
        }
    }

    // ---- epilogue t = 16: odd half finalizes cell 31 ----
    if (half) {
        FINSTORE(Hp, kbp[31], mb[0], vb[0], cb[0], mapsB + 16 * 512)
    }
#undef BARRIER
#undef STAGE_WRITE
#undef STAGE_ISSUE
#undef TAPS_READ
#undef FINSTORE
#undef SWAP32
#undef REDUCE
}

// ===========================================================================
// FALLBACK PATH (round-1 kernels, used only if workspace is too small)
// ===========================================================================
__global__ void lbki_accum(const float* __restrict__ pc,
                           float* __restrict__ y_sum,
                           float* __restrict__ sq_sum,
                           float* __restrict__ k_bar,
                           int npts) {
    __shared__ float kval_s[27];
    if (threadIdx.x < 27) kval_s[threadIdx.x] = kval_of(threadIdx.x);
    __syncthreads();

    int lane = threadIdx.x & 63;
    int wave = threadIdx.x >> 6;
    int p = blockIdx.x * (blockDim.x >> 6) + wave;
    if (p >= npts) return;

    const float* row = pc + (size_t)p * 67;
    int gx, gy, gz;
    base_cell(row, &gx, &gy, &gz);
    float f = row[3 + lane];
    float ff = f * f;

    #pragma unroll
    for (int o = 0; o < 27; ++o) {
        float kv = kval_s[o];
        if (kv <= 0.0f) continue;
        int nx = gx + (o / 9) - 1;
        int ny = gy + ((o / 3) % 3) - 1;
        int nz = gz + (o % 3) - 1;
        if ((unsigned)nx >= (unsigned)GXD) continue;
        if ((unsigned)ny >= (unsigned)GYD) continue;
        if ((unsigned)nz >= (unsigned)GZD) continue;
        size_t g = ((size_t)nx * GYD + ny) * GZD + nz;
        atomicAdd(&y_sum[g * DD + lane], kv * f);
        atomicAdd(&sq_sum[g * DD + lane], kv * ff);
        if (lane == 0) atomicAdd(&k_bar[g], kv);
    }
}

__global__ void lbki_finalize(const float* __restrict__ mean_map,
                              const float* __restrict__ var_map,
                              const float* __restrict__ conf_map,
                              float* __restrict__ out_mean,
                              float* __restrict__ out_var,
                              float* __restrict__ out_conf) {
    int lane = threadIdx.x & 63;
    int wave = threadIdx.x >> 6;
    int g = blockIdx.x * (blockDim.x >> 6) + wave;
    if (g >= GCELLS) return;

    float kb   = out_conf[g];
    float conf = conf_map[g];

    size_t idx = (size_t)g * DD + lane;
    float ys   = out_mean[idx];
    float sq   = out_var[idx];
    float mean = mean_map[idx];
    float var  = var_map[idx];

    float ybar  = ys / (kb + EPSV);
    float Sbar  = sq - 2.0f * ybar * ys + ybar * ybar * kb;
    float denom = conf + kb + EPSV;
    float dm    = ybar - mean;
    float scal  = conf * kb / denom;

    out_mean[idx] = (conf * mean + kb * ybar) / denom;
    out_var[idx]  = var + Sbar + scal * dm * dm;
    if (lane == 0) out_conf[g] = conf + kb;
}

// ===========================================================================
extern "C" void kernel_launch(void* const* d_in, const int* in_sizes, int n_in,
                              void* d_out, int out_size, void* d_ws, size_t ws_size,
                              hipStream_t stream) {
    const float* mean_map = (const float*)d_in[0];
    const float* var_map  = (const float*)d_in[1];
    const float* conf_map = (const float*)d_in[2];
    const float* pc       = (const float*)d_in[3];
    int npts = in_sizes[3] / 67;

    float* out      = (float*)d_out;
    float* out_mean = out;
    float* out_var  = out + (size_t)GCELLS * DD;
    float* out_conf = out + (size_t)2 * GCELLS * DD;

    const size_t M0_ELEMS = (size_t)GCELLS;
    const size_t MM_ELEMS = (size_t)GCELLS * 128;      // no sentinel needed
    const size_t WS_NEEDED = (M0_ELEMS + MM_ELEMS) * sizeof(float);

    if (ws_size >= WS_NEEDED) {
        float* M0 = (float*)d_ws;
        float* MM = M0 + M0_ELEMS;

        // single small memset: counts (2MB)
        hipMemsetAsync(M0, 0, M0_ELEMS * sizeof(float), stream);

        int wpb = 4;
        int pblocks = (npts + wpb - 1) / wpb;
        lbki_zero_rows<<<pblocks, 256, 0, stream>>>(pc, (float2*)MM, npts);
        lbki_build<<<pblocks, 256, 0, stream>>>(pc, M0, MM, npts);

        // host-side column weights (double precision, cast to f32)
        KvCols ka;
        for (int c = 0; c < 9; ++c) {
            int ox = c / 3 - 1, oy = c % 3 - 1;
            for (int k = 0; k < 2; ++k) {   // k = |oz|
                double dx = ox * (double)VOXX;
                double dy = oy * (double)VOXY;
                double dz = k  * (double)VOXZ;
                double d  = sqrt(dx * dx + dy * dy + dz * dz);
                double ang = 2.0 * (double)PIF * d / (double)ELL;
                double v = (1.0 / 3.0) * (2.0 + cos(ang)) * (1.0 - d / (double)ELL)
                         + (1.0 / (2.0 * (double)PIF)) * sin(ang);
                if (d >= (double)ELL) v = 0.0;
                v = v < 0.0 ? 0.0 : (v > 1.0 ? 1.0 : v);
                if (k == 0) ka.w0[c] = (float)v; else ka.w1[c] = (float)v;
            }
        }

        int sblocks = (GXD * GYD) / 8;   // 2048 blocks, % 8 == 0
        lbki_stencil_colD<<<sblocks, 512, 0, stream>>>(M0, MM,
                                                       mean_map, var_map, conf_map,
                                                       out_mean, out_var, out_conf,
                                                       ka);
    } else {
        hipMemsetAsync(d_out, 0, (size_t)out_size * sizeof(float), stream);
        int wpb = 4;
        int blocks = (npts + wpb - 1) / wpb;
        lbki_accum<<<blocks, 256, 0, stream>>>(pc, out_mean, out_var, out_conf, npts);
        int fblocks = GCELLS / 4;
        lbki_finalize<<<fblocks, 256, 0, stream>>>(mean_map, var_map, conf_map,
                                                   out_mean, out_var, out_conf);
    }
}